// Round 1
// baseline (1623.959 us; speedup 1.0000x reference)
//
#include <hip/hip_runtime.h>
#include <hip/hip_bf16.h>

#define T_ 4
#define C_ 64
#define H_ 128
#define W_ 128
#define CI_ 16
#define PS_ 7
#define WSZ_ 27
#define NC_ 729       // WSZ*WSZ candidates per query
#define S0_ 4
#define KS_ 100
#define NQ_ 1024      // 32*32 queries per frame
#define PD_ 784       // CI*PS*PS patch dim
#define SCALE_ 10.0f

// ---------------- conv 3x3, 64->16, pad=1 ----------------
__global__ __launch_bounds__(256) void conv3x3_kernel(
    const float* __restrict__ vid, const float* __restrict__ gw,
    const float* __restrict__ gb, float* __restrict__ v1) {
  __shared__ float w[C_ * 9];
  int co = blockIdx.y, t = blockIdx.z;
  for (int i = threadIdx.x; i < C_ * 9; i += 256) w[i] = gw[co * C_ * 9 + i];
  __syncthreads();
  int pix = blockIdx.x * 256 + threadIdx.x;   // 0..16383
  int i = pix >> 7, j = pix & 127;
  float acc = gb[co];
  for (int c = 0; c < C_; ++c) {
    const float* vb = vid + ((t * C_ + c) * H_) * W_;
    const float* wb = w + c * 9;
#pragma unroll
    for (int ki = 0; ki < 3; ++ki) {
      int ii = i + ki - 1;
      if (ii < 0 || ii >= H_) continue;
      const float* row = vb + ii * W_;
#pragma unroll
      for (int kj = 0; kj < 3; ++kj) {
        int jj = j + kj - 1;
        if (jj < 0 || jj >= W_) continue;
        acc += wb[ki * 3 + kj] * row[jj];
      }
    }
  }
  v1[((t * CI_ + co) * H_) * W_ + pix] = acc;
}

// ---------------- conv 1x1, 64->16 ----------------
__global__ __launch_bounds__(256) void conv1x1_kernel(
    const float* __restrict__ vid, const float* __restrict__ tw,
    const float* __restrict__ tb, float* __restrict__ v2) {
  __shared__ float w[C_ * CI_];   // transposed: w[c*CI+o] = tw[o*C+c]
  int t = blockIdx.y;
  for (int i = threadIdx.x; i < C_ * CI_; i += 256) {
    int o = i & (CI_ - 1), c = i >> 4;
    w[i] = tw[o * C_ + c];
  }
  __syncthreads();
  int pix = blockIdx.x * 256 + threadIdx.x;
  float acc[CI_];
#pragma unroll
  for (int o = 0; o < CI_; ++o) acc[o] = tb[o];
  for (int c = 0; c < C_; ++c) {
    float x = vid[(t * C_ + c) * (H_ * W_) + pix];
#pragma unroll
    for (int o = 0; o < CI_; ++o) acc[o] += w[c * CI_ + o] * x;
  }
#pragma unroll
  for (int o = 0; o < CI_; ++o) v2[(t * CI_ + o) * (H_ * W_) + pix] = acc[o];
}

// ---------------- Zc: fold counts (t/c independent) ----------------
__global__ void zc_kernel(float* __restrict__ Zc) {
  int idx = blockIdx.x * blockDim.x + threadIdx.x;   // over NQ*49
  if (idx >= NQ_ * PS_ * PS_) return;
  int q = idx / 49, rs = idx % 49;
  int qi = (q >> 5) * S0_, qj = (q & 31) * S0_;
  int r = rs / 7, s = rs % 7;
  atomicAdd(&Zc[min(qi + r, H_ - 1) * W_ + min(qj + s, W_ - 1)], 1.0f);
}

// ---------------- fused scores + exact top-100 + softmax numerators ----------------
__global__ __launch_bounds__(256) void scores_topk_kernel(
    const float* __restrict__ v1, int* __restrict__ sel_n,
    float* __restrict__ sel_w, float* __restrict__ wsum_out) {
  __shared__ float qp[PD_];
  __shared__ float dist[NC_];
  __shared__ float red[256];
  int q = blockIdx.x, t = blockIdx.y;
  int qi = (q >> 5) * S0_, qj = (q & 31) * S0_;
  const float* vt = v1 + t * CI_ * H_ * W_;

  // stage query patch (clamped)
  for (int d = threadIdx.x; d < PD_; d += 256) {
    int c = d / 49, rs = d % 49;
    int r = rs / 7, s = rs % 7;
    qp[d] = vt[(c * H_ + min(qi + r, H_ - 1)) * W_ + min(qj + s, W_ - 1)];
  }
  __syncthreads();

  // dists for 729 candidates
  for (int cand = threadIdx.x; cand < NC_; cand += 256) {
    int a = cand / WSZ_, b = cand % WSZ_;
    int ni = min(max(qi + a - 13, 0), H_ - 1);
    int nj = min(max(qj + b - 13, 0), W_ - 1);
    int rows[PS_], cols[PS_];
#pragma unroll
    for (int r = 0; r < PS_; ++r) rows[r] = min(ni + r, H_ - 1);
#pragma unroll
    for (int s = 0; s < PS_; ++s) cols[s] = min(nj + s, W_ - 1);
    float acc = 0.f;
    for (int c = 0; c < CI_; ++c) {
      const float* vb = vt + c * H_ * W_;
#pragma unroll
      for (int r = 0; r < PS_; ++r) {
        const float* rowp = vb + rows[r] * W_;
#pragma unroll
        for (int s = 0; s < PS_; ++s)
          acc += qp[c * 49 + r * 7 + s] * rowp[cols[s]];
      }
    }
    dist[cand] = acc;
  }
  __syncthreads();

  // block max (= top-1 value, softmax shift)
  float m = -INFINITY;
  for (int k = threadIdx.x; k < NC_; k += 256) m = fmaxf(m, dist[k]);
  red[threadIdx.x] = m;
  __syncthreads();
  for (int off = 128; off > 0; off >>= 1) {
    if (threadIdx.x < off) red[threadIdx.x] = fmaxf(red[threadIdx.x], red[threadIdx.x + off]);
    __syncthreads();
  }
  float dmax = red[0];
  __syncthreads();

  // counting selection: rank = #{k beats cand}; jax top_k tie-break = lower index first
  float mysum = 0.f;
  int out_base = (t * NQ_ + q) * KS_;
  for (int cand = threadIdx.x; cand < NC_; cand += 256) {
    float val = dist[cand];
    int rank = 0;
    for (int k = 0; k < NC_; ++k) {
      float dk = dist[k];
      rank += (dk > val) || (dk == val && k < cand);
    }
    if (rank < KS_) {
      int a = cand / WSZ_, b = cand % WSZ_;
      int ni = min(max(qi + a - 13, 0), H_ - 1);
      int nj = min(max(qj + b - 13, 0), W_ - 1);
      float e = __expf(SCALE_ * (val - dmax));
      sel_n[out_base + rank] = ni * W_ + nj;
      sel_w[out_base + rank] = e;
      mysum += e;
    }
  }
  red[threadIdx.x] = mysum;
  __syncthreads();
  for (int off = 128; off > 0; off >>= 1) {
    if (threadIdx.x < off) red[threadIdx.x] += red[threadIdx.x + off];
    __syncthreads();
  }
  if (threadIdx.x == 0) wsum_out[t * NQ_ + q] = red[0];
}

// ---------------- weighted patch aggregation + overlap-add fold ----------------
__global__ __launch_bounds__(256) void agg_kernel(
    const float* __restrict__ v2, const int* __restrict__ sel_n,
    const float* __restrict__ sel_w, const float* __restrict__ wsum,
    float* __restrict__ Y) {
  __shared__ int s_n[KS_];
  __shared__ float s_w[KS_];
  int q = blockIdx.x, t = blockIdx.y;
  int base = (t * NQ_ + q) * KS_;
  if (threadIdx.x < KS_) {
    s_n[threadIdx.x] = sel_n[base + threadIdx.x];
    s_w[threadIdx.x] = sel_w[base + threadIdx.x] / wsum[t * NQ_ + q];
  }
  __syncthreads();
  int qi = (q >> 5) * S0_, qj = (q & 31) * S0_;
  const float* vt = v2 + t * CI_ * H_ * W_;
  for (int d = threadIdx.x; d < PD_; d += 256) {
    int c = d / 49, rs = d % 49;
    int r = rs / 7, s = rs % 7;
    float acc = 0.f;
    for (int k = 0; k < KS_; ++k) {
      int n = s_n[k];
      int ni = n >> 7, nj = n & 127;
      acc += s_w[k] * vt[(c * H_ + min(ni + r, H_ - 1)) * W_ + min(nj + s, W_ - 1)];
    }
    atomicAdd(&Y[((t * CI_ + c) * H_ + min(qi + r, H_ - 1)) * W_ + min(qj + s, W_ - 1)], acc);
  }
}

// ---------------- normalize by fold counts ----------------
__global__ void norm_kernel(float* __restrict__ Y, const float* __restrict__ Zc) {
  int idx = blockIdx.x * blockDim.x + threadIdx.x;
  if (idx >= T_ * CI_ * H_ * W_) return;
  Y[idx] /= Zc[idx & (H_ * W_ - 1)];
}

extern "C" void kernel_launch(void* const* d_in, const int* in_sizes, int n_in,
                              void* d_out, int out_size, void* d_ws, size_t ws_size,
                              hipStream_t stream) {
  const float* vid     = (const float*)d_in[0];
  const float* g_w     = (const float*)d_in[1];
  const float* g_b     = (const float*)d_in[2];
  const float* theta_w = (const float*)d_in[3];
  const float* theta_b = (const float*)d_in[4];
  float* Y = (float*)d_out;

  // workspace layout (floats): v1 | v2 | sel_n | sel_w | wsum | Zc  (~12 MB)
  float* v1    = (float*)d_ws;
  float* v2    = v1 + (size_t)T_ * CI_ * H_ * W_;              // +1048576
  int*   sel_n = (int*)(v2 + (size_t)T_ * CI_ * H_ * W_);      // +1048576
  float* sel_w = (float*)(sel_n + (size_t)T_ * NQ_ * KS_);     // +409600
  float* wsumv = sel_w + (size_t)T_ * NQ_ * KS_;               // +409600
  float* Zc    = wsumv + (size_t)T_ * NQ_;                     // +4096

  hipMemsetAsync(Y, 0, (size_t)T_ * CI_ * H_ * W_ * sizeof(float), stream);
  hipMemsetAsync(Zc, 0, (size_t)H_ * W_ * sizeof(float), stream);

  conv3x3_kernel<<<dim3(H_ * W_ / 256, CI_, T_), 256, 0, stream>>>(vid, g_w, g_b, v1);
  conv1x1_kernel<<<dim3(H_ * W_ / 256, T_), 256, 0, stream>>>(vid, theta_w, theta_b, v2);
  zc_kernel<<<(NQ_ * PS_ * PS_ + 255) / 256, 256, 0, stream>>>(Zc);
  scores_topk_kernel<<<dim3(NQ_, T_), 256, 0, stream>>>(v1, sel_n, sel_w, wsumv);
  agg_kernel<<<dim3(NQ_, T_), 256, 0, stream>>>(v2, sel_n, sel_w, wsumv, Y);
  norm_kernel<<<(T_ * CI_ * H_ * W_ + 255) / 256, 256, 0, stream>>>(Y, Zc);
}

// Round 2
// 774.423 us; speedup vs baseline: 2.0970x; 2.0970x over previous
//
#include <hip/hip_runtime.h>
#include <hip/hip_bf16.h>

#define T_ 4
#define C_ 64
#define H_ 128
#define W_ 128
#define CI_ 16
#define PS_ 7
#define WSZ_ 27
#define NC_ 729       // 27*27 candidates per query
#define S0_ 4
#define KS_ 100
#define NQ_ 1024      // 32*32 queries per frame
#define SCALE_ 10.0f
#define HW_ (H_*W_)

// ---------------- conv 3x3, 64->16, pad=1, channels-last output ----------------
// grid (64, 2, 4): y = co-group of 8. Each thread = 1 pixel, 8 output channels.
__global__ __launch_bounds__(256) void conv3x3_kernel(
    const float* __restrict__ vid, const float* __restrict__ gw,
    const float* __restrict__ gb, float* __restrict__ v1cl) {
  __shared__ float ws[8 * C_ * 9];   // ws[c*72 + co*9 + k]
  const int g = blockIdx.y, t = blockIdx.z;
  for (int m = threadIdx.x; m < 8 * C_ * 9; m += 256) {
    int c = m / 72, rem = m - c * 72;
    int co = rem / 9, k = rem - co * 9;
    ws[m] = gw[((g * 8 + co) * C_ + c) * 9 + k];
  }
  __syncthreads();
  const int pix = blockIdx.x * 256 + threadIdx.x;
  const int i = pix >> 7, j = pix & 127;
  float acc[8];
#pragma unroll
  for (int co = 0; co < 8; ++co) acc[co] = gb[g * 8 + co];
  for (int c = 0; c < C_; ++c) {
    const float* vb = vid + ((size_t)(t * C_ + c)) * HW_;
    float n[9];
#pragma unroll
    for (int ki = 0; ki < 3; ++ki) {
      int ii = i + ki - 1;
      bool rok = (ii >= 0) && (ii < H_);
#pragma unroll
      for (int kj = 0; kj < 3; ++kj) {
        int jj = j + kj - 1;
        bool ok = rok && (jj >= 0) && (jj < W_);
        n[ki * 3 + kj] = ok ? vb[ii * W_ + jj] : 0.f;
      }
    }
    const float* wc = ws + c * 72;
#pragma unroll
    for (int co = 0; co < 8; ++co)
#pragma unroll
      for (int k = 0; k < 9; ++k)
        acc[co] = fmaf(wc[co * 9 + k], n[k], acc[co]);
  }
  float4* out = (float4*)v1cl + ((size_t)t * HW_ + pix) * 4 + g * 2;
  out[0] = make_float4(acc[0], acc[1], acc[2], acc[3]);
  out[1] = make_float4(acc[4], acc[5], acc[6], acc[7]);
}

// ---------------- conv 1x1, 64->16, channels-last output ----------------
__global__ __launch_bounds__(256) void conv1x1_kernel(
    const float* __restrict__ vid, const float* __restrict__ tw,
    const float* __restrict__ tb, float* __restrict__ v2cl) {
  __shared__ float w[C_ * CI_];   // w[c*16 + o]
  const int t = blockIdx.y;
  for (int m = threadIdx.x; m < C_ * CI_; m += 256) {
    int o = m & 15, c = m >> 4;
    w[m] = tw[o * C_ + c];
  }
  __syncthreads();
  const int pix = blockIdx.x * 256 + threadIdx.x;
  float acc[CI_];
#pragma unroll
  for (int o = 0; o < CI_; ++o) acc[o] = tb[o];
  for (int c = 0; c < C_; ++c) {
    float x = vid[((size_t)(t * C_ + c)) * HW_ + pix];
#pragma unroll
    for (int o = 0; o < CI_; ++o) acc[o] = fmaf(w[c * 16 + o], x, acc[o]);
  }
  float4* out = (float4*)v2cl + ((size_t)t * HW_ + pix) * 4;
#pragma unroll
  for (int cc = 0; cc < 4; ++cc)
    out[cc] = make_float4(acc[cc * 4], acc[cc * 4 + 1], acc[cc * 4 + 2], acc[cc * 4 + 3]);
}

// ---------------- Zc: fold counts ----------------
__global__ void zc_kernel(float* __restrict__ Zc) {
  int idx = blockIdx.x * blockDim.x + threadIdx.x;
  if (idx >= NQ_ * PS_ * PS_) return;
  int q = idx / 49, rs = idx - q * 49;
  int qi = (q >> 5) * S0_, qj = (q & 31) * S0_;
  int r = rs / 7, s = rs - r * 7;
  atomicAdd(&Zc[min(qi + r, H_ - 1) * W_ + min(qj + s, W_ - 1)], 1.0f);
}

// ---------------- fused dists (region-tiled) + top-100 (histogram select) + softmax ----------------
// Block = 128 threads per (q, t). Items: tid<108 -> (ai = tid>>2, bg = tid&3),
// candidate rows a = min(a_lo+ai, 26), 7 candidates b = b_lo + bg*7 + j.
// Low-clamped candidates (a<a_lo | b<b_lo) are bit-exact duplicates -> replication.
__global__ __launch_bounds__(128) void scores_kernel(
    const float* __restrict__ v1cl, int* __restrict__ sel_n,
    float* __restrict__ sel_w, float* __restrict__ wsum_out) {
  __shared__ float4 Rs[33 * 33];          // one 4-channel chunk of the 33x33 region
  __shared__ float dist[NC_];
  __shared__ unsigned int ukey[NC_];
  __shared__ float red[128];
  __shared__ unsigned int hist[256];
  __shared__ int sfx[64];
  __shared__ unsigned int scal[4];        // [0]=beta [1]=cnt_gt [2]=cursor

  const int tid = threadIdx.x;
  const int q = blockIdx.x, t = blockIdx.y;
  const int qi = (q >> 5) * S0_, qj = (q & 31) * S0_;
  const int a_lo = max(13 - qi, 0), b_lo = max(13 - qj, 0);

  const int ai = tid >> 2, bgi = tid & 3;
  const int a = min(a_lo + ai, 26);
  const int b0 = b_lo + bgi * 7;
  const bool active = (tid < 108) && (b0 <= 26);
  const int y_hi = min(12, 32 - b0);

  float acc[7];
#pragma unroll
  for (int j = 0; j < 7; ++j) acc[j] = 0.f;

  const float4* v1q = (const float4*)v1cl + (size_t)t * HW_ * 4;

#pragma unroll 1
  for (int cc = 0; cc < 4; ++cc) {
    __syncthreads();
    // stage chunk cc of the clamped region
    for (int p = tid; p < 1089; p += 128) {
      int u = p / 33, v = p - u * 33;
      int row = min(max(qi - 13 + u, 0), H_ - 1);
      int col = min(max(qj - 13 + v, 0), W_ - 1);
      Rs[p] = v1q[(row * W_ + col) * 4 + cc];
    }
    __syncthreads();
    if (active) {
#pragma unroll 1
      for (int r = 0; r < 7; ++r) {
        float4 qv[7];
#pragma unroll
        for (int s = 0; s < 7; ++s) qv[s] = Rs[(13 + r) * 33 + 13 + s];
        const float4* base = &Rs[(a + r) * 33 + b0];
#pragma unroll
        for (int y = 0; y < 13; ++y) {
          if (y <= y_hi) {
            float4 v = base[y];
#pragma unroll
            for (int j = 0; j < 7; ++j) {
              int s = y - j;
              if (s >= 0 && s < 7) {
                float4 qq = qv[s];
                acc[j] = fmaf(qq.x, v.x, acc[j]);
                acc[j] = fmaf(qq.y, v.y, acc[j]);
                acc[j] = fmaf(qq.z, v.z, acc[j]);
                acc[j] = fmaf(qq.w, v.w, acc[j]);
              }
            }
          }
        }
      }
    }
  }
  // write computed dists (duplicate writers write bit-identical values)
  if (active) {
#pragma unroll
    for (int j = 0; j < 7; ++j) {
      int b = b0 + j;
      if (b <= 26) dist[a * 27 + b] = acc[j];
    }
  }
  __syncthreads();
  // replicate low-clamped duplicates; zero hist; init cursor
  for (int k = tid; k < NC_; k += 128) {
    int aa = k / 27, bb = k - aa * 27;
    if (aa < a_lo || bb < b_lo)
      dist[k] = dist[max(aa, a_lo) * 27 + max(bb, b_lo)];
  }
  for (int h = tid; h < 256; h += 128) hist[h] = 0;
  if (tid == 0) scal[2] = 0;
  __syncthreads();
  // keys + local max
  float lmax = -INFINITY;
  for (int k = tid; k < NC_; k += 128) {
    float d = dist[k];
    lmax = fmaxf(lmax, d);
    unsigned int u = __float_as_uint(d);
    ukey[k] = u ^ (((unsigned int)((int)u >> 31)) | 0x80000000u);
  }
  red[tid] = lmax;
  __syncthreads();
  for (int off = 64; off > 0; off >>= 1) {
    if (tid < off) red[tid] = fmaxf(red[tid], red[tid + off]);
    __syncthreads();
  }
  const float dmax = red[0];
  __syncthreads();
  // histogram of top byte
  for (int k = tid; k < NC_; k += 128) atomicAdd(&hist[ukey[k] >> 24], 1u);
  __syncthreads();
  // suffix-sum over 64 groups of 4 bins, find boundary bin
  if (tid < 64)
    sfx[tid] = (int)(hist[tid * 4] + hist[tid * 4 + 1] + hist[tid * 4 + 2] + hist[tid * 4 + 3]);
  __syncthreads();
  for (int off = 1; off < 64; off <<= 1) {
    int v = 0;
    if (tid < 64 && tid + off < 64) v = sfx[tid + off];
    __syncthreads();
    if (tid < 64) sfx[tid] += v;
    __syncthreads();
  }
  if (tid < 64) {
    int s4 = (int)(hist[tid * 4] + hist[tid * 4 + 1] + hist[tid * 4 + 2] + hist[tid * 4 + 3]);
    int above = sfx[tid] - s4;
    if (above < KS_ && sfx[tid] >= KS_) {
      int run = above;
#pragma unroll
      for (int bb = 3; bb >= 0; --bb) {
        int h = (int)hist[tid * 4 + bb];
        if (run + h >= KS_) { scal[0] = (unsigned int)(tid * 4 + bb); scal[1] = (unsigned int)run; break; }
        run += h;
      }
    }
  }
  __syncthreads();
  const unsigned int beta = scal[0];
  float lsum = 0.f;
  const size_t outb = ((size_t)t * NQ_ + q) * KS_;
  for (int k = tid; k < NC_; k += 128) {
    unsigned int key = ukey[k];
    unsigned int bin = key >> 24;
    bool sel = false;
    if (bin > beta) {
      sel = true;
    } else if (bin == beta) {
      // exact rank with lax.top_k tie-break (lower index wins among equal values)
      int rank = 0;
      for (int k2 = 0; k2 < NC_; ++k2) {
        unsigned int k2k = ukey[k2];
        rank += (int)((k2k > key) || (k2k == key && k2 < k));
      }
      sel = rank < KS_;
    }
    if (sel) {
      unsigned int slot = atomicAdd(&scal[2], 1u);
      int aa = k / 27, bb = k - aa * 27;
      int ni = min(max(qi + aa - 13, 0), H_ - 1);
      int nj = min(max(qj + bb - 13, 0), W_ - 1);
      float wv = __expf(SCALE_ * (dist[k] - dmax));
      sel_n[outb + slot] = (ni << 7) | nj;
      sel_w[outb + slot] = wv;
      lsum += wv;
    }
  }
  __syncthreads();
  red[tid] = lsum;
  __syncthreads();
  for (int off = 64; off > 0; off >>= 1) {
    if (tid < off) red[tid] += red[tid + off];
    __syncthreads();
  }
  if (tid == 0) wsum_out[t * NQ_ + q] = red[0];
}

// ---------------- weighted aggregation + fold (region-tiled) ----------------
__global__ __launch_bounds__(64) void agg_kernel(
    const float* __restrict__ v2cl, const int* __restrict__ sel_n,
    const float* __restrict__ sel_w, const float* __restrict__ wsum,
    float* __restrict__ Y) {
  __shared__ float4 Rs[33 * 33];
  __shared__ int s_off[KS_];
  __shared__ float s_w[KS_];
  const int tid = threadIdx.x;
  const int q = blockIdx.x, t = blockIdx.y;
  const int qi = (q >> 5) * S0_, qj = (q & 31) * S0_;
  const size_t base = ((size_t)t * NQ_ + q) * KS_;
  const float inv = 1.0f / wsum[t * NQ_ + q];
  for (int k = tid; k < KS_; k += 64) {
    int n = sel_n[base + k];
    int ni = n >> 7, nj = n & 127;
    s_off[k] = (ni - qi + 13) * 33 + (nj - qj + 13);
    s_w[k] = sel_w[base + k] * inv;
  }
  const float4* v2q = (const float4*)v2cl + (size_t)t * HW_ * 4;
  const int r = tid / 7, s = tid - r * 7;   // valid for tid < 49
  const int myo = r * 33 + s;
#pragma unroll 1
  for (int cc = 0; cc < 4; ++cc) {
    __syncthreads();
    for (int p = tid; p < 1089; p += 64) {
      int u = p / 33, v = p - u * 33;
      int row = min(max(qi - 13 + u, 0), H_ - 1);
      int col = min(max(qj - 13 + v, 0), W_ - 1);
      Rs[p] = v2q[(row * W_ + col) * 4 + cc];
    }
    __syncthreads();
    if (tid < 49) {
      float ax = 0.f, ay = 0.f, az = 0.f, aw = 0.f;
      for (int k = 0; k < KS_; ++k) {
        float w = s_w[k];
        float4 v = Rs[s_off[k] + myo];
        ax = fmaf(w, v.x, ax); ay = fmaf(w, v.y, ay);
        az = fmaf(w, v.z, az); aw = fmaf(w, v.w, aw);
      }
      int oi = min(qi + r, H_ - 1), oj = min(qj + s, W_ - 1);
      float* yb = Y + (((size_t)t * CI_ + cc * 4) * H_ + oi) * W_ + oj;
      atomicAdd(yb, ax);
      atomicAdd(yb + HW_, ay);
      atomicAdd(yb + 2 * HW_, az);
      atomicAdd(yb + 3 * HW_, aw);
    }
  }
}

// ---------------- normalize by fold counts ----------------
__global__ void norm_kernel(float* __restrict__ Y, const float* __restrict__ Zc) {
  int idx = blockIdx.x * blockDim.x + threadIdx.x;
  if (idx >= T_ * CI_ * HW_) return;
  Y[idx] /= Zc[idx & (HW_ - 1)];
}

extern "C" void kernel_launch(void* const* d_in, const int* in_sizes, int n_in,
                              void* d_out, int out_size, void* d_ws, size_t ws_size,
                              hipStream_t stream) {
  const float* vid     = (const float*)d_in[0];
  const float* g_w     = (const float*)d_in[1];
  const float* g_b     = (const float*)d_in[2];
  const float* theta_w = (const float*)d_in[3];
  const float* theta_b = (const float*)d_in[4];
  float* Y = (float*)d_out;

  // workspace layout (floats): v1cl | v2cl | sel_n | sel_w | wsum | Zc
  float* v1cl  = (float*)d_ws;
  float* v2cl  = v1cl + (size_t)T_ * HW_ * CI_;                // +1048576
  int*   sel_n = (int*)(v2cl + (size_t)T_ * HW_ * CI_);        // +1048576
  float* sel_w = (float*)(sel_n + (size_t)T_ * NQ_ * KS_);     // +409600
  float* wsumv = sel_w + (size_t)T_ * NQ_ * KS_;               // +409600
  float* Zc    = wsumv + (size_t)T_ * NQ_;                     // +4096

  hipMemsetAsync(Y, 0, (size_t)out_size * sizeof(float), stream);
  hipMemsetAsync(Zc, 0, (size_t)HW_ * sizeof(float), stream);

  conv3x3_kernel<<<dim3(HW_ / 256, 2, T_), 256, 0, stream>>>(vid, g_w, g_b, v1cl);
  conv1x1_kernel<<<dim3(HW_ / 256, T_), 256, 0, stream>>>(vid, theta_w, theta_b, v2cl);
  zc_kernel<<<(NQ_ * PS_ * PS_ + 255) / 256, 256, 0, stream>>>(Zc);
  scores_kernel<<<dim3(NQ_, T_), 128, 0, stream>>>(v1cl, sel_n, sel_w, wsumv);
  agg_kernel<<<dim3(NQ_, T_), 64, 0, stream>>>(v2cl, sel_n, sel_w, wsumv, Y);
  norm_kernel<<<(T_ * CI_ * HW_ + 255) / 256, 256, 0, stream>>>(Y, Zc);
}

// Round 3
// 430.259 us; speedup vs baseline: 3.7744x; 1.7999x over previous
//
#include <hip/hip_runtime.h>
#include <hip/hip_bf16.h>

#define T_ 4
#define C_ 64
#define H_ 128
#define W_ 128
#define CI_ 16
#define PS_ 7
#define NC_ 729       // 27*27 candidates per query
#define S0_ 4
#define KS_ 100
#define NQ_ 1024      // 32*32 queries per frame
#define SCALE_ 10.0f
#define HW_ (H_*W_)
#define RH_ 33        // region rows
#define RW_ 40        // padded region row stride (in float4)
#define LCAP_ 768

// ---------------- conv 3x3, 64->16, pad=1, chunk-major float4 output ----------------
// v1cs layout: [cc(4)][t][h][w] of float4 (4 channels per chunk)
__global__ __launch_bounds__(256) void conv3x3_kernel(
    const float* __restrict__ vid, const float* __restrict__ gw,
    const float* __restrict__ gb, float4* __restrict__ v1cs) {
  __shared__ float ws[8 * C_ * 9];   // ws[c*72 + co*9 + k]
  const int g = blockIdx.y, t = blockIdx.z;
  for (int m = threadIdx.x; m < 8 * C_ * 9; m += 256) {
    int c = m / 72, rem = m - c * 72;
    int co = rem / 9, k = rem - co * 9;
    ws[m] = gw[((g * 8 + co) * C_ + c) * 9 + k];
  }
  __syncthreads();
  const int pix = blockIdx.x * 256 + threadIdx.x;
  const int i = pix >> 7, j = pix & 127;
  float acc[8];
#pragma unroll
  for (int co = 0; co < 8; ++co) acc[co] = gb[g * 8 + co];
  for (int c = 0; c < C_; ++c) {
    const float* vb = vid + ((size_t)(t * C_ + c)) * HW_;
    float n[9];
#pragma unroll
    for (int ki = 0; ki < 3; ++ki) {
      int ii = i + ki - 1;
      bool rok = (ii >= 0) && (ii < H_);
#pragma unroll
      for (int kj = 0; kj < 3; ++kj) {
        int jj = j + kj - 1;
        bool ok = rok && (jj >= 0) && (jj < W_);
        n[ki * 3 + kj] = ok ? vb[ii * W_ + jj] : 0.f;
      }
    }
    const float* wc = ws + c * 72;
#pragma unroll
    for (int co = 0; co < 8; ++co)
#pragma unroll
      for (int k = 0; k < 9; ++k)
        acc[co] = fmaf(wc[co * 9 + k], n[k], acc[co]);
  }
  v1cs[((size_t)(g * 2) * T_ + t) * HW_ + pix]     = make_float4(acc[0], acc[1], acc[2], acc[3]);
  v1cs[((size_t)(g * 2 + 1) * T_ + t) * HW_ + pix] = make_float4(acc[4], acc[5], acc[6], acc[7]);
}

// ---------------- conv 1x1, 64->16, chunk-major float4 output ----------------
__global__ __launch_bounds__(256) void conv1x1_kernel(
    const float* __restrict__ vid, const float* __restrict__ tw,
    const float* __restrict__ tb, float4* __restrict__ v2cs) {
  __shared__ float w[C_ * CI_];   // w[c*16 + o]
  const int t = blockIdx.y;
  for (int m = threadIdx.x; m < C_ * CI_; m += 256) {
    int o = m & 15, c = m >> 4;
    w[m] = tw[o * C_ + c];
  }
  __syncthreads();
  const int pix = blockIdx.x * 256 + threadIdx.x;
  float acc[CI_];
#pragma unroll
  for (int o = 0; o < CI_; ++o) acc[o] = tb[o];
  for (int c = 0; c < C_; ++c) {
    float x = vid[((size_t)(t * C_ + c)) * HW_ + pix];
#pragma unroll
    for (int o = 0; o < CI_; ++o) acc[o] = fmaf(w[c * 16 + o], x, acc[o]);
  }
#pragma unroll
  for (int cc = 0; cc < 4; ++cc)
    v2cs[((size_t)cc * T_ + t) * HW_ + pix] =
        make_float4(acc[cc * 4], acc[cc * 4 + 1], acc[cc * 4 + 2], acc[cc * 4 + 3]);
}

// ---------------- Zc: fold counts ----------------
__global__ void zc_kernel(float* __restrict__ Zc) {
  int idx = blockIdx.x * blockDim.x + threadIdx.x;
  if (idx >= NQ_ * PS_ * PS_) return;
  int q = idx / 49, rs = idx - q * 49;
  int qi = (q >> 5) * S0_, qj = (q & 31) * S0_;
  int r = rs / 7, s = rs - r * 7;
  atomicAdd(&Zc[min(qi + r, H_ - 1) * W_ + min(qj + s, W_ - 1)], 1.0f);
}

// ---------------- dists: branch-free region-tiled correlation ----------------
// One block per (q,t). Items: tid<189 -> ai=tid/7 (row), bg=tid%7 (col group of 4).
// Row remap a=min(a_lo+ai,26), col remap bs=min(b_lo+4bg,23): covers all non-duplicate
// candidates; low-clamped dupes resolved by remapped load in select_kernel.
__global__ __launch_bounds__(256) void dist_kernel(
    const float4* __restrict__ v1cs, float* __restrict__ distG) {
  __shared__ float4 Rs[RH_ * RW_];
  const int tid = threadIdx.x;
  const int q = blockIdx.x, t = blockIdx.y;
  const int qi = (q >> 5) * S0_, qj = (q & 31) * S0_;
  const int a_lo = max(13 - qi, 0), b_lo = max(13 - qj, 0);
  const bool active = tid < 189;
  const int ai = tid / 7, bg = tid - ai * 7;
  const int a = min(a_lo + ai, 26);
  const int bs = min(b_lo + 4 * bg, 23);
  float4 acc[4];
#pragma unroll
  for (int j = 0; j < 4; ++j) acc[j] = make_float4(0.f, 0.f, 0.f, 0.f);

#pragma unroll 1
  for (int cc = 0; cc < 4; ++cc) {
    __syncthreads();
    const float4* src = v1cs + ((size_t)cc * T_ + t) * HW_;
    for (int p = tid; p < RH_ * RW_; p += 256) {
      int u = p / RW_, v = p - u * RW_;
      int row = min(max(qi - 13 + u, 0), H_ - 1);
      int col = min(max(qj - 13 + v, 0), W_ - 1);
      Rs[p] = src[row * W_ + col];
    }
    __syncthreads();
    if (active) {
#pragma unroll 1
      for (int r = 0; r < 7; ++r) {
        float4 qv[7], rw[10];
        const float4* qrow = &Rs[(13 + r) * RW_ + 13];
#pragma unroll
        for (int s = 0; s < 7; ++s) qv[s] = qrow[s];
        const float4* crow = &Rs[(a + r) * RW_ + bs];
#pragma unroll
        for (int y = 0; y < 10; ++y) rw[y] = crow[y];
#pragma unroll
        for (int j = 0; j < 4; ++j)
#pragma unroll
          for (int s = 0; s < 7; ++s) {
            float4 qq = qv[s], vv = rw[j + s];
            acc[j].x = fmaf(qq.x, vv.x, acc[j].x);
            acc[j].y = fmaf(qq.y, vv.y, acc[j].y);
            acc[j].z = fmaf(qq.z, vv.z, acc[j].z);
            acc[j].w = fmaf(qq.w, vv.w, acc[j].w);
          }
      }
    }
  }
  if (active) {
    float* out = distG + ((size_t)t * NQ_ + q) * NC_ + a * 27 + bs;
#pragma unroll
    for (int j = 0; j < 4; ++j)
      out[j] = (acc[j].x + acc[j].y) + (acc[j].z + acc[j].w);
  }
}

// ---------------- select: histogram top-100 + exact tie-break + softmax ----------------
__global__ __launch_bounds__(256) void select_kernel(
    const float* __restrict__ distG, int* __restrict__ sel_n,
    float* __restrict__ sel_w, float* __restrict__ wsum_out) {
  __shared__ float dist[NC_];
  __shared__ unsigned int ukey[NC_];
  __shared__ float red[256];
  __shared__ unsigned int hist[256];
  __shared__ int sfx[64];
  __shared__ int lk[LCAP_];
  __shared__ unsigned int lkey[LCAP_];
  __shared__ unsigned int scal[4];   // 0=beta 1=run 2=out cursor 3=list len

  const int tid = threadIdx.x;
  const int q = blockIdx.x, t = blockIdx.y;
  const int qi = (q >> 5) * S0_, qj = (q & 31) * S0_;
  const int a_lo = max(13 - qi, 0), b_lo = max(13 - qj, 0);
  const size_t base = ((size_t)t * NQ_ + q) * NC_;

  for (int h = tid; h < 256; h += 256) hist[h] = 0;
  if (tid == 0) { scal[2] = 0; scal[3] = 0; }
  // load with duplicate remap (low-clamped candidates == candidate at (max(a,a_lo),max(b,b_lo)))
  for (int k = tid; k < NC_; k += 256) {
    int aa = k / 27, bb = k - aa * 27;
    int kk = max(aa, a_lo) * 27 + max(bb, b_lo);
    float d = distG[base + kk];
    dist[k] = d;
    unsigned int u = __float_as_uint(d);
    ukey[k] = u ^ (((unsigned int)((int)u >> 31)) | 0x80000000u);
  }
  __syncthreads();
  // max reduce
  float lmax = -INFINITY;
  for (int k = tid; k < NC_; k += 256) lmax = fmaxf(lmax, dist[k]);
  red[tid] = lmax;
  __syncthreads();
  for (int off = 128; off > 0; off >>= 1) {
    if (tid < off) red[tid] = fmaxf(red[tid], red[tid + off]);
    __syncthreads();
  }
  const float dmax = red[0];
  __syncthreads();
  // histogram of top byte
  for (int k = tid; k < NC_; k += 256) atomicAdd(&hist[ukey[k] >> 24], 1u);
  __syncthreads();
  // suffix-sum over 64 groups of 4 bins, locate boundary bin beta
  if (tid < 64)
    sfx[tid] = (int)(hist[tid * 4] + hist[tid * 4 + 1] + hist[tid * 4 + 2] + hist[tid * 4 + 3]);
  __syncthreads();
  for (int off = 1; off < 64; off <<= 1) {
    int v = 0;
    if (tid < 64 && tid + off < 64) v = sfx[tid + off];
    __syncthreads();
    if (tid < 64) sfx[tid] += v;
    __syncthreads();
  }
  if (tid < 64) {
    int s4 = (int)(hist[tid * 4] + hist[tid * 4 + 1] + hist[tid * 4 + 2] + hist[tid * 4 + 3]);
    int above = sfx[tid] - s4;
    if (above < KS_ && sfx[tid] >= KS_) {
      int run = above;
#pragma unroll
      for (int bb = 3; bb >= 0; --bb) {
        int h = (int)hist[tid * 4 + bb];
        if (run + h >= KS_) { scal[0] = (unsigned int)(tid * 4 + bb); scal[1] = (unsigned int)run; break; }
        run += h;
      }
    }
  }
  __syncthreads();
  const unsigned int beta = scal[0];
  const int run = (int)scal[1];
  const size_t outb = ((size_t)t * NQ_ + q) * KS_;
  float lsum = 0.f;
  // pass 1: bins above beta auto-selected; boundary bin -> compact list
  for (int k = tid; k < NC_; k += 256) {
    unsigned int key = ukey[k];
    unsigned int bin = key >> 24;
    if (bin > beta) {
      unsigned int slot = atomicAdd(&scal[2], 1u);
      int aa = k / 27, bb = k - aa * 27;
      int ni = min(max(qi + aa - 13, 0), H_ - 1);
      int nj = min(max(qj + bb - 13, 0), W_ - 1);
      float wv = __expf(SCALE_ * (dist[k] - dmax));
      sel_n[outb + slot] = (ni << 7) | nj;
      sel_w[outb + slot] = wv;
      lsum += wv;
    } else if (bin == beta) {
      unsigned int pos = atomicAdd(&scal[3], 1u);
      if (pos < LCAP_) { lk[pos] = k; lkey[pos] = key; }
    }
  }
  __syncthreads();
  const int L = min((int)scal[3], LCAP_);
  // pass 2: exact rank within boundary bin (lax.top_k tie-break: lower index wins)
  for (int i = tid; i < L; i += 256) {
    unsigned int key = lkey[i];
    int k = lk[i];
    int cnt = run;
    for (int m = 0; m < L; ++m)
      cnt += (int)((lkey[m] > key) || (lkey[m] == key && lk[m] < k));
    if (cnt < KS_) {
      unsigned int slot = atomicAdd(&scal[2], 1u);
      int aa = k / 27, bb = k - aa * 27;
      int ni = min(max(qi + aa - 13, 0), H_ - 1);
      int nj = min(max(qj + bb - 13, 0), W_ - 1);
      float wv = __expf(SCALE_ * (dist[k] - dmax));
      sel_n[outb + slot] = (ni << 7) | nj;
      sel_w[outb + slot] = wv;
      lsum += wv;
    }
  }
  __syncthreads();
  red[tid] = lsum;
  __syncthreads();
  for (int off = 128; off > 0; off >>= 1) {
    if (tid < off) red[tid] += red[tid + off];
    __syncthreads();
  }
  if (tid == 0) wsum_out[t * NQ_ + q] = red[0];
}

// ---------------- weighted aggregation + fold (direct L2 gather) ----------------
// 256 threads = 4 chunk-groups of 64; lane<49 handles one (r,s) of the 7x7 patch.
__global__ __launch_bounds__(256) void agg_kernel(
    const float4* __restrict__ v2cs, const int* __restrict__ sel_n,
    const float* __restrict__ sel_w, const float* __restrict__ wsum,
    float* __restrict__ Y) {
  __shared__ int s_ni[KS_], s_nj[KS_];
  __shared__ float s_w[KS_];
  const int tid = threadIdx.x;
  const int q = blockIdx.x, t = blockIdx.y;
  const int qi = (q >> 5) * S0_, qj = (q & 31) * S0_;
  const size_t base = ((size_t)t * NQ_ + q) * KS_;
  if (tid < KS_) {
    int n = sel_n[base + tid];
    s_ni[tid] = n >> 7;
    s_nj[tid] = n & 127;
    s_w[tid] = sel_w[base + tid] / wsum[t * NQ_ + q];
  }
  __syncthreads();
  const int cc = tid >> 6, lane = tid & 63;
  if (lane >= 49) return;
  const int r = lane / 7, s = lane - r * 7;
  const float4* src = v2cs + ((size_t)cc * T_ + t) * HW_;
  float4 acc = make_float4(0.f, 0.f, 0.f, 0.f);
#pragma unroll 4
  for (int k = 0; k < KS_; ++k) {
    int ri = min(s_ni[k] + r, H_ - 1);
    int ci = min(s_nj[k] + s, W_ - 1);
    float4 v = src[ri * W_ + ci];
    float w = s_w[k];
    acc.x = fmaf(w, v.x, acc.x);
    acc.y = fmaf(w, v.y, acc.y);
    acc.z = fmaf(w, v.z, acc.z);
    acc.w = fmaf(w, v.w, acc.w);
  }
  const int oi = min(qi + r, H_ - 1), oj = min(qj + s, W_ - 1);
  float* yb = Y + (((size_t)t * CI_ + cc * 4) * H_ + oi) * W_ + oj;
  atomicAdd(yb, acc.x);
  atomicAdd(yb + HW_, acc.y);
  atomicAdd(yb + 2 * HW_, acc.z);
  atomicAdd(yb + 3 * HW_, acc.w);
}

// ---------------- normalize by fold counts ----------------
__global__ void norm_kernel(float* __restrict__ Y, const float* __restrict__ Zc) {
  int idx = blockIdx.x * blockDim.x + threadIdx.x;
  if (idx >= T_ * CI_ * HW_) return;
  Y[idx] /= Zc[idx & (HW_ - 1)];
}

extern "C" void kernel_launch(void* const* d_in, const int* in_sizes, int n_in,
                              void* d_out, int out_size, void* d_ws, size_t ws_size,
                              hipStream_t stream) {
  const float* vid     = (const float*)d_in[0];
  const float* g_w     = (const float*)d_in[1];
  const float* g_b     = (const float*)d_in[2];
  const float* theta_w = (const float*)d_in[3];
  const float* theta_b = (const float*)d_in[4];
  float* Y = (float*)d_out;

  // workspace (floats): v1cs | v2cs | distG | sel_n | sel_w | wsum | Zc  (~24 MB)
  float* v1cs  = (float*)d_ws;
  float* v2cs  = v1cs + (size_t)4 * T_ * HW_ * 4;              // 1048576
  float* distG = v2cs + (size_t)4 * T_ * HW_ * 4;              // 1048576
  int*   sel_n = (int*)(distG + (size_t)T_ * NQ_ * NC_);       // 2985984
  float* sel_w = (float*)(sel_n + (size_t)T_ * NQ_ * KS_);     // 409600
  float* wsumv = sel_w + (size_t)T_ * NQ_ * KS_;               // 409600
  float* Zc    = wsumv + (size_t)T_ * NQ_;                     // 4096

  hipMemsetAsync(Y, 0, (size_t)out_size * sizeof(float), stream);
  hipMemsetAsync(Zc, 0, (size_t)HW_ * sizeof(float), stream);

  conv3x3_kernel<<<dim3(HW_ / 256, 2, T_), 256, 0, stream>>>(vid, g_w, g_b, (float4*)v1cs);
  conv1x1_kernel<<<dim3(HW_ / 256, T_), 256, 0, stream>>>(vid, theta_w, theta_b, (float4*)v2cs);
  zc_kernel<<<(NQ_ * PS_ * PS_ + 255) / 256, 256, 0, stream>>>(Zc);
  dist_kernel<<<dim3(NQ_, T_), 256, 0, stream>>>((const float4*)v1cs, distG);
  select_kernel<<<dim3(NQ_, T_), 256, 0, stream>>>(distG, sel_n, sel_w, wsumv);
  agg_kernel<<<dim3(NQ_, T_), 256, 0, stream>>>((const float4*)v2cs, sel_n, sel_w, wsumv, Y);
  norm_kernel<<<(T_ * CI_ * HW_ + 255) / 256, 256, 0, stream>>>(Y, Zc);
}